// Round 1
// baseline (739.756 us; speedup 1.0000x reference)
//
#include <hip/hip_runtime.h>
#include <hip/hip_bf16.h>
#include <stdint.h>

#define IN_DIM 384
#define HID 64
#define C1 256   // 4 heads * 64
#define C2 128   // 2 heads * 64

typedef unsigned int uint32;

static __device__ __forceinline__ float bf2f(unsigned short u){
    return __uint_as_float(((uint32)u) << 16);
}
static __device__ __forceinline__ unsigned short f2bf(float x){
    uint32 u = __float_as_uint(x);
    return (unsigned short)((u + 0x7FFFu + ((u >> 16) & 1u)) >> 16);
}

// ---------------- CSR build ----------------
__global__ void k_zero(int* deg, int* cur, int N){
    int i = blockIdx.x*256 + threadIdx.x;
    if (i < N){ deg[i] = 0; cur[i] = 0; }
}
__global__ void k_hist(const int* __restrict__ ei, int* deg, int E){
    int i = blockIdx.x*256 + threadIdx.x;
    if (i < E) atomicAdd(&deg[ei[E + i]], 1);
}
__global__ void k_scan1(const int* __restrict__ deg, int* rowptr, int* part, int N){
    __shared__ int s[256];
    int tid = threadIdx.x;
    int i = blockIdx.x*256 + tid;
    int v = (i < N) ? deg[i] : 0;
    s[tid] = v; __syncthreads();
    for (int off = 1; off < 256; off <<= 1){
        int t = (tid >= off) ? s[tid - off] : 0;
        __syncthreads();
        s[tid] += t;
        __syncthreads();
    }
    if (i < N) rowptr[i] = s[tid] - v;      // exclusive within block
    if (tid == 255) part[blockIdx.x] = s[tid];
}
__global__ void k_scan2(int* part, int nb){
    __shared__ int s[512];
    int tid = threadIdx.x;
    int v = (tid < nb) ? part[tid] : 0;
    s[tid] = v; __syncthreads();
    for (int off = 1; off < 512; off <<= 1){
        int t = (tid >= off) ? s[tid - off] : 0;
        __syncthreads();
        s[tid] += t;
        __syncthreads();
    }
    if (tid < nb) part[tid] = s[tid] - v;   // exclusive
}
__global__ void k_scan3(int* rowptr, const int* __restrict__ part, int N, int E){
    int i = blockIdx.x*256 + threadIdx.x;
    if (i < N) rowptr[i] += part[blockIdx.x];
    if (i == 0) rowptr[N] = E;
}
__global__ void k_scatter(const int* __restrict__ ei, const int* __restrict__ rowptr,
                          int* cur, int* colx, int E){
    int i = blockIdx.x*256 + threadIdx.x;
    if (i < E){
        int d = ei[E + i];
        int pos = atomicAdd(&cur[d], 1);
        colx[rowptr[d] + pos] = ei[i];
    }
}

// ---------------- GEMM1: h1 = [x | pad] @ W1  (f32 in, bf16 out) ----------------
// block 256 threads, 32 rows/block, thread = (rowg 0..3)*(8 rows) x (colg 0..63)*(4 cols)
__global__ __launch_bounds__(256) void k_gemm1(const float* __restrict__ x,
        const float* __restrict__ W1, const float* __restrict__ pad,
        unsigned short* __restrict__ h1, int N)
{
    __shared__ float xs[32][IN_DIM];
    const int tid = threadIdx.x;
    const int n0 = blockIdx.x*32;
    for (int it = tid; it < 32*(IN_DIM/4); it += 256){
        int row = it / (IN_DIM/4);
        int k4  = it % (IN_DIM/4);
        int n = n0 + row;
        float4 v;
        if (n < N) v = *(const float4*)&x[(size_t)n*IN_DIM + k4*4];
        else       v = make_float4(0.f,0.f,0.f,0.f);
        *(float4*)&xs[row][k4*4] = v;
    }
    __syncthreads();
    const int colg = tid & 63;
    const int rowg = tid >> 6;
    const int col = colg*4;
    float c1v[4];
    #pragma unroll
    for (int j = 0; j < 4; j++){
        c1v[j] = pad[0]*W1[(size_t)(IN_DIM+0)*C1 + col + j]
               + pad[1]*W1[(size_t)(IN_DIM+1)*C1 + col + j]
               + pad[2]*W1[(size_t)(IN_DIM+2)*C1 + col + j];
    }
    float acc[8][4];
    #pragma unroll
    for (int r = 0; r < 8; r++)
        #pragma unroll
        for (int j = 0; j < 4; j++) acc[r][j] = c1v[j];

    for (int k4 = 0; k4 < IN_DIM/4; ++k4){
        float4 w0 = *(const float4*)&W1[(size_t)(k4*4+0)*C1 + col];
        float4 w1 = *(const float4*)&W1[(size_t)(k4*4+1)*C1 + col];
        float4 w2 = *(const float4*)&W1[(size_t)(k4*4+2)*C1 + col];
        float4 w3 = *(const float4*)&W1[(size_t)(k4*4+3)*C1 + col];
        #pragma unroll
        for (int r = 0; r < 8; r++){
            float4 xv = *(const float4*)&xs[rowg*8 + r][k4*4];
            acc[r][0] += xv.x*w0.x + xv.y*w1.x + xv.z*w2.x + xv.w*w3.x;
            acc[r][1] += xv.x*w0.y + xv.y*w1.y + xv.z*w2.y + xv.w*w3.y;
            acc[r][2] += xv.x*w0.z + xv.y*w1.z + xv.z*w2.z + xv.w*w3.z;
            acc[r][3] += xv.x*w0.w + xv.y*w1.w + xv.z*w2.w + xv.w*w3.w;
        }
    }
    #pragma unroll
    for (int r = 0; r < 8; r++){
        int n = n0 + rowg*8 + r;
        if (n < N){
            ushort4 o;
            o.x = f2bf(acc[r][0]); o.y = f2bf(acc[r][1]);
            o.z = f2bf(acc[r][2]); o.w = f2bf(acc[r][3]);
            *(ushort4*)&h1[(size_t)n*C1 + col] = o;
        }
    }
}

// ---------------- GEMM2: h2 = x2 @ W2 (bf16 in, bf16 out) ----------------
// block 256, 32 rows/block, thread = (rowg 0..7)*(4 rows) x (colg 0..31)*(4 cols)
__global__ __launch_bounds__(256) void k_gemm2(const unsigned short* __restrict__ x2,
        const float* __restrict__ W2, unsigned short* __restrict__ h2, int N)
{
    __shared__ float xs[32][C1];
    const int tid = threadIdx.x;
    const int n0 = blockIdx.x*32;
    for (int it = tid; it < 32*(C1/4); it += 256){
        int row = it / (C1/4);
        int c4  = it % (C1/4);
        int n = n0 + row;
        ushort4 v;
        if (n < N) v = *(const ushort4*)&x2[(size_t)n*C1 + c4*4];
        else { v.x = v.y = v.z = v.w = 0; }
        xs[row][c4*4+0] = bf2f(v.x);
        xs[row][c4*4+1] = bf2f(v.y);
        xs[row][c4*4+2] = bf2f(v.z);
        xs[row][c4*4+3] = bf2f(v.w);
    }
    __syncthreads();
    const int colg = tid & 31;
    const int rowg = tid >> 5;
    const int col = colg*4;
    float acc[4][4];
    #pragma unroll
    for (int r = 0; r < 4; r++)
        #pragma unroll
        for (int j = 0; j < 4; j++) acc[r][j] = 0.f;

    for (int k4 = 0; k4 < C1/4; ++k4){
        float4 w0 = *(const float4*)&W2[(size_t)(k4*4+0)*C2 + col];
        float4 w1 = *(const float4*)&W2[(size_t)(k4*4+1)*C2 + col];
        float4 w2 = *(const float4*)&W2[(size_t)(k4*4+2)*C2 + col];
        float4 w3 = *(const float4*)&W2[(size_t)(k4*4+3)*C2 + col];
        #pragma unroll
        for (int r = 0; r < 4; r++){
            float4 xv = *(const float4*)&xs[rowg*4 + r][k4*4];
            acc[r][0] += xv.x*w0.x + xv.y*w1.x + xv.z*w2.x + xv.w*w3.x;
            acc[r][1] += xv.x*w0.y + xv.y*w1.y + xv.z*w2.y + xv.w*w3.y;
            acc[r][2] += xv.x*w0.z + xv.y*w1.z + xv.z*w2.z + xv.w*w3.z;
            acc[r][3] += xv.x*w0.w + xv.y*w1.w + xv.z*w2.w + xv.w*w3.w;
        }
    }
    #pragma unroll
    for (int r = 0; r < 4; r++){
        int n = n0 + rowg*4 + r;
        if (n < N){
            ushort4 o;
            o.x = f2bf(acc[r][0]); o.y = f2bf(acc[r][1]);
            o.z = f2bf(acc[r][2]); o.w = f2bf(acc[r][3]);
            *(ushort4*)&h2[(size_t)n*C2 + col] = o;
        }
    }
}

// ---------------- attention logits: al = einsum('nhc,hc->nh') ----------------
__global__ __launch_bounds__(256) void k_al1(const unsigned short* __restrict__ h1,
        const float* __restrict__ asrc, const float* __restrict__ adst,
        float* __restrict__ als, float* __restrict__ ald, int N)
{
    int lane = threadIdx.x & 63, wid = threadIdx.x >> 6;
    int n = blockIdx.x*4 + wid;
    if (n >= N) return;
    int c0 = lane*4, head = c0 >> 6, ca = c0 & 63;
    ushort4 v = *(const ushort4*)&h1[(size_t)n*C1 + c0];
    float h0 = bf2f(v.x), hb = bf2f(v.y), hc = bf2f(v.z), hd = bf2f(v.w);
    float4 a4 = *(const float4*)&asrc[head*HID + ca];
    float4 d4 = *(const float4*)&adst[head*HID + ca];
    float ps = h0*a4.x + hb*a4.y + hc*a4.z + hd*a4.w;
    float pd = h0*d4.x + hb*d4.y + hc*d4.z + hd*d4.w;
    #pragma unroll
    for (int m = 8; m >= 1; m >>= 1){
        ps += __shfl_xor(ps, m, 64);
        pd += __shfl_xor(pd, m, 64);
    }
    if ((lane & 15) == 0){ als[(size_t)n*4 + head] = ps; ald[(size_t)n*4 + head] = pd; }
}
__global__ __launch_bounds__(256) void k_al2(const unsigned short* __restrict__ h2,
        const float* __restrict__ asrc, const float* __restrict__ adst,
        float* __restrict__ als, float* __restrict__ ald, int N)
{
    int lane = threadIdx.x & 63, wid = threadIdx.x >> 6;
    int n = blockIdx.x*4 + wid;
    if (n >= N) return;
    int c0 = lane*2, head = c0 >> 6, ca = c0 & 63;
    uint32 v = *(const uint32*)&h2[(size_t)n*C2 + c0];
    float h0 = bf2f((unsigned short)(v & 0xffff)), hb = bf2f((unsigned short)(v >> 16));
    float2 a2 = *(const float2*)&asrc[head*HID + ca];
    float2 d2 = *(const float2*)&adst[head*HID + ca];
    float ps = h0*a2.x + hb*a2.y;
    float pd = h0*d2.x + hb*d2.y;
    #pragma unroll
    for (int m = 16; m >= 1; m >>= 1){
        ps += __shfl_xor(ps, m, 64);
        pd += __shfl_xor(pd, m, 64);
    }
    if ((lane & 31) == 0){ als[(size_t)n*2 + head] = ps; ald[(size_t)n*2 + head] = pd; }
}

// ---------------- per-node online-softmax aggregation (one wave per node) ----------
template<int HEADS, int CPL, int LAYER>
__global__ __launch_bounds__(256) void k_agg(const unsigned short* __restrict__ hlin,
        const float* __restrict__ als, const float* __restrict__ ald,
        const int* __restrict__ rowptr, const int* __restrict__ colx,
        const float* __restrict__ bias,
        const float* __restrict__ pad, const float* __restrict__ gw, const float* __restrict__ gb,
        unsigned short* __restrict__ out_bf, float* __restrict__ out_f, int N)
{
    constexpr int C = HEADS*64;
    int lane = threadIdx.x & 63, wid = threadIdx.x >> 6;
    int n = blockIdx.x*4 + wid;
    if (n >= N) return;
    int c0 = lane*CPL;
    int head = c0 >> 6;
    float myald = ald[(size_t)n*HEADS + head];
    float m = -INFINITY, den = 0.f;
    float acc[CPL];
    #pragma unroll
    for (int j = 0; j < CPL; j++) acc[j] = 0.f;
    int base = rowptr[n];
    int cnt = rowptr[n+1] - base;
    for (int i = -1; i < cnt; i++){          // i==-1 is the self loop
        int s = (i < 0) ? n : colx[base + i];
        float e = als[(size_t)s*HEADS + head] + myald;
        e = (e > 0.f) ? e : 0.2f*e;
        float mnew = fmaxf(m, e);
        float scale = __expf(m - mnew);      // 0 on first iter (m=-inf)
        float p = __expf(e - mnew);
        den = den*scale + p;
        float hv[CPL];
        if constexpr (CPL == 4){
            ushort4 v = *(const ushort4*)&hlin[(size_t)s*C + c0];
            hv[0] = bf2f(v.x); hv[1] = bf2f(v.y); hv[2] = bf2f(v.z); hv[3] = bf2f(v.w);
        } else {
            uint32 v = *(const uint32*)&hlin[(size_t)s*C + c0];
            hv[0] = bf2f((unsigned short)(v & 0xffff));
            hv[1] = bf2f((unsigned short)(v >> 16));
        }
        #pragma unroll
        for (int j = 0; j < CPL; j++) acc[j] = acc[j]*scale + p*hv[j];
        m = mnew;
    }
    float inv = 1.f/(den + 1e-16f);
    if constexpr (LAYER == 1){
        unsigned short o[CPL];
        #pragma unroll
        for (int j = 0; j < CPL; j++){
            float r = acc[j]*inv + bias[c0 + j];
            r = (r > 0.f) ? r : (__expf(r) - 1.f);   // elu
            o[j] = f2bf(r);
        }
        if constexpr (CPL == 4){
            ushort4 ov; ov.x = o[0]; ov.y = o[1]; ov.z = o[2]; ov.w = o[3];
            *(ushort4*)&out_bf[(size_t)n*C + c0] = ov;
        }
    } else {
        #pragma unroll
        for (int j = 0; j < CPL; j++){
            float r = acc[j]*inv + bias[c0 + j];
            r = (r > 0.f) ? r : (__expf(r) - 1.f);   // elu
            int cc = (c0 + j) & 63;
            float g = pad[0]*gw[0*HID + cc] + pad[1]*gw[1*HID + cc] + pad[2]*gw[2*HID + cc] + gb[cc];
            g = 1.f/(1.f + __expf(-g));              // constant emotion gate
            out_f[(size_t)n*C + c0 + j] = r*g;
        }
    }
}

// ---------------- attention-score MLP ----------------
__global__ __launch_bounds__(256) void k_attn(const float* __restrict__ hfin,
        const float* __restrict__ aw1, const float* __restrict__ ab1,
        const float* __restrict__ aw2, const float* __restrict__ ab2,
        float* __restrict__ attn, int N)
{
    __shared__ float hs[4][C2];
    int lane = threadIdx.x & 63, wid = threadIdx.x >> 6;
    int n = blockIdx.x*4 + wid;
    bool valid = (n < N);
    if (valid){
        float2 v = *(const float2*)&hfin[(size_t)n*C2 + lane*2];
        hs[wid][lane*2]   = v.x;
        hs[wid][lane*2+1] = v.y;
    }
    __syncthreads();
    if (!valid) return;
    float a = ab1[lane];
    #pragma unroll 4
    for (int c = 0; c < C2; c++) a += hs[wid][c]*aw1[(size_t)c*HID + lane];
    a = fmaxf(a, 0.f);
    float part = a*aw2[lane];
    #pragma unroll
    for (int m = 32; m >= 1; m >>= 1) part += __shfl_xor(part, m, 64);
    if (lane == 0) attn[n] = 1.f/(1.f + __expf(-(part + ab2[0])));
}

extern "C" void kernel_launch(void* const* d_in, const int* in_sizes, int n_in,
                              void* d_out, int out_size, void* d_ws, size_t ws_size,
                              hipStream_t stream)
{
    const float* x    = (const float*)d_in[0];
    const int*   ei   = (const int*)  d_in[1];
    const float* pad  = (const float*)d_in[2];
    const float* W1   = (const float*)d_in[3];
    const float* as1  = (const float*)d_in[4];
    const float* ad1  = (const float*)d_in[5];
    const float* b1   = (const float*)d_in[6];
    const float* W2   = (const float*)d_in[7];
    const float* as2  = (const float*)d_in[8];
    const float* ad2  = (const float*)d_in[9];
    const float* b2   = (const float*)d_in[10];
    const float* aw1  = (const float*)d_in[11];
    const float* ab1  = (const float*)d_in[12];
    const float* aw2  = (const float*)d_in[13];
    const float* ab2  = (const float*)d_in[14];
    const float* gw   = (const float*)d_in[15];
    const float* gb   = (const float*)d_in[16];

    const int N = in_sizes[0] / IN_DIM;
    const int E = in_sizes[1] / 2;

    float* outh    = (float*)d_out;
    float* outattn = outh + (size_t)N*C2;

    char* w = (char*)d_ws;
    auto alloc = [&](size_t bytes)->char*{
        char* p = w;
        w += (bytes + 255) & ~(size_t)255;
        return p;
    };
    unsigned short* h1  = (unsigned short*)alloc((size_t)N*C1*2);
    unsigned short* x2  = (unsigned short*)alloc((size_t)N*C1*2);
    unsigned short* h2  = (unsigned short*)alloc((size_t)N*C2*2);
    float* als1 = (float*)alloc((size_t)N*4*4);
    float* ald1 = (float*)alloc((size_t)N*4*4);
    float* als2 = (float*)alloc((size_t)N*2*4);
    float* ald2 = (float*)alloc((size_t)N*2*4);
    int* deg    = (int*)alloc((size_t)N*4);
    int* cur    = (int*)alloc((size_t)N*4);
    int* rowptr = (int*)alloc((size_t)(N+1)*4);
    int* colx   = (int*)alloc((size_t)E*4);
    int* part   = (int*)alloc(512*4);

    const int nbN = (N + 255)/256;
    const int nbE = (E + 255)/256;
    const int nbW = (N + 3)/4;      // wave-per-node kernels
    const int nbG = (N + 31)/32;    // gemm row blocks

    k_zero   <<<nbN, 256, 0, stream>>>(deg, cur, N);
    k_hist   <<<nbE, 256, 0, stream>>>(ei, deg, E);
    k_scan1  <<<nbN, 256, 0, stream>>>(deg, rowptr, part, N);
    k_scan2  <<<1, 512, 0, stream>>>(part, nbN);
    k_scan3  <<<nbN, 256, 0, stream>>>(rowptr, part, N, E);
    k_scatter<<<nbE, 256, 0, stream>>>(ei, rowptr, cur, colx, E);

    k_gemm1<<<nbG, 256, 0, stream>>>(x, W1, pad, h1, N);
    k_al1  <<<nbW, 256, 0, stream>>>(h1, as1, ad1, als1, ald1, N);
    k_agg<4,4,1><<<nbW, 256, 0, stream>>>(h1, als1, ald1, rowptr, colx, b1,
                                          nullptr, nullptr, nullptr, x2, nullptr, N);

    k_gemm2<<<nbG, 256, 0, stream>>>(x2, W2, h2, N);
    k_al2  <<<nbW, 256, 0, stream>>>(h2, as2, ad2, als2, ald2, N);
    k_agg<2,2,2><<<nbW, 256, 0, stream>>>(h2, als2, ald2, rowptr, colx, b2,
                                          pad, gw, gb, nullptr, outh, N);

    k_attn <<<nbW, 256, 0, stream>>>(outh, aw1, ab1, aw2, ab2, outattn, N);
}

// Round 2
// 448.428 us; speedup vs baseline: 1.6497x; 1.6497x over previous
//
#include <hip/hip_runtime.h>
#include <hip/hip_bf16.h>
#include <stdint.h>

#define IN_DIM 384
#define HID 64
#define C1 256   // 4 heads * 64
#define C2 128   // 2 heads * 64

typedef unsigned int uint32;
typedef __bf16 bf16x8 __attribute__((ext_vector_type(8)));
typedef float f32x4 __attribute__((ext_vector_type(4)));

static __device__ __forceinline__ float bf2f(unsigned short u){
    return __uint_as_float(((uint32)u) << 16);
}
static __device__ __forceinline__ unsigned short f2bf(float x){
    uint32 u = __float_as_uint(x);
    return (unsigned short)((u + 0x7FFFu + ((u >> 16) & 1u)) >> 16);
}

// ---------------- CSR build ----------------
__global__ void k_zero(int* deg, int* cur, int N){
    int i = blockIdx.x*256 + threadIdx.x;
    if (i < N){ deg[i] = 0; cur[i] = 0; }
}
__global__ void k_hist(const int* __restrict__ ei, int* deg, int E){
    int i = blockIdx.x*256 + threadIdx.x;
    if (i < E) atomicAdd(&deg[ei[E + i]], 1);
}
__global__ void k_scan1(const int* __restrict__ deg, int* rowptr, int* part, int N){
    __shared__ int s[256];
    int tid = threadIdx.x;
    int i = blockIdx.x*256 + tid;
    int v = (i < N) ? deg[i] : 0;
    s[tid] = v; __syncthreads();
    for (int off = 1; off < 256; off <<= 1){
        int t = (tid >= off) ? s[tid - off] : 0;
        __syncthreads();
        s[tid] += t;
        __syncthreads();
    }
    if (i < N) rowptr[i] = s[tid] - v;
    if (tid == 255) part[blockIdx.x] = s[tid];
}
__global__ void k_scan2(int* part, int nb){
    __shared__ int s[512];
    int tid = threadIdx.x;
    int v = (tid < nb) ? part[tid] : 0;
    s[tid] = v; __syncthreads();
    for (int off = 1; off < 512; off <<= 1){
        int t = (tid >= off) ? s[tid - off] : 0;
        __syncthreads();
        s[tid] += t;
        __syncthreads();
    }
    if (tid < nb) part[tid] = s[tid] - v;
}
__global__ void k_scan3(int* rowptr, const int* __restrict__ part, int N, int E){
    int i = blockIdx.x*256 + threadIdx.x;
    if (i < N) rowptr[i] += part[blockIdx.x];
    if (i == 0) rowptr[N] = E;
}
__global__ void k_scatter(const int* __restrict__ ei, const int* __restrict__ rowptr,
                          int* cur, int* colx, int E){
    int i = blockIdx.x*256 + threadIdx.x;
    if (i < E){
        int d = ei[E + i];
        int pos = atomicAdd(&cur[d], 1);
        colx[rowptr[d] + pos] = ei[i];
    }
}

// ---------------- weight pre-swizzle into MFMA fragment order ----------------
// Wf[unit = s*ntiles+ct][lane][j]  holds  W[k = s*32 + 4*(l>>4) + (j&3) + 16*(j>>2)][ct*16 + (l&15)]
__global__ __launch_bounds__(256) void k_cvtW(const float* __restrict__ W,
        unsigned short* __restrict__ Wf, int ncol, int ntiles, int nunits){
    int unit = blockIdx.x*4 + (threadIdx.x >> 6);
    if (unit >= nunits) return;
    int l = threadIdx.x & 63;
    int s = unit / ntiles, ct = unit % ntiles;
    int col = ct*16 + (l & 15);
    int g = l >> 4;
    unsigned short o[8];
    #pragma unroll
    for (int j = 0; j < 8; j++){
        int k = s*32 + g*4 + (j & 3) + (j >> 2)*16;
        o[j] = f2bf(W[(size_t)k*ncol + col]);
    }
    ushort4* dst = (ushort4*)&Wf[((size_t)unit*64 + l)*8];
    dst[0] = make_ushort4(o[0], o[1], o[2], o[3]);
    dst[1] = make_ushort4(o[4], o[5], o[6], o[7]);
}

__global__ void k_padbias(const float* __restrict__ W1, const float* __restrict__ pad,
                          float* __restrict__ c1v){
    int c = threadIdx.x;
    c1v[c] = pad[0]*W1[(size_t)(IN_DIM+0)*C1 + c]
           + pad[1]*W1[(size_t)(IN_DIM+1)*C1 + c]
           + pad[2]*W1[(size_t)(IN_DIM+2)*C1 + c];
}

// ---------------- GEMM1 (MFMA): h1 = [x | pad] @ W1, bf16 out ----------------
// block = 256 thr (4 waves), tile 64 rows x 256 cols; wave w -> cols [w*64, w*64+64)
// swapped operands: acc = mfma(Wfrag, Xfrag) so lane holds 4 consecutive cols of one node
__global__ __launch_bounds__(256) void k_gemm1_mfma(const float* __restrict__ x,
        const unsigned short* __restrict__ Wf, const float* __restrict__ c1v,
        unsigned short* __restrict__ h1, int N)
{
    __shared__ unsigned short Af[4*64*8];   // [rowtile][lane][elem] fragment order
    const int tid = threadIdx.x;
    const int l   = tid & 63;
    const int w   = tid >> 6;
    const int n0  = blockIdx.x * 64;

    // staging: thread covers row sr, k-cols sc..sc+7 of the 32-wide K step
    const int sr  = tid >> 2;
    const int sc  = (tid & 3) * 8;
    const int gb  = (tid & 1) * 2;         // k 0..7 -> lanegroups {0,1}; 8..15 -> {2,3}
    const int jhi = (tid & 3) >> 1;        // k>=16 -> elems 4..7
    const int woff1 = (( (sr >> 4)*64 + (sr & 15) + 16*gb )*8) + jhi*4;
    const int woff2 = woff1 + 16*8;        // lanegroup +1
    const bool srow_ok = (n0 + sr) < N;
    const float* xrow = x + (size_t)(n0 + sr)*IN_DIM + sc;

    f32x4 acc[4][4];
    #pragma unroll
    for (int i = 0; i < 4; i++)
        #pragma unroll
        for (int rt = 0; rt < 4; rt++)
            acc[i][rt] = (f32x4){0.f, 0.f, 0.f, 0.f};

    float4 pa, pb;
    if (srow_ok){ pa = *(const float4*)(xrow); pb = *(const float4*)(xrow + 4); }
    else        { pa = make_float4(0,0,0,0); pb = pa; }

    for (int s = 0; s < 12; ++s){
        __syncthreads();
        ushort4 oa = make_ushort4(f2bf(pa.x), f2bf(pa.y), f2bf(pa.z), f2bf(pa.w));
        ushort4 ob = make_ushort4(f2bf(pb.x), f2bf(pb.y), f2bf(pb.z), f2bf(pb.w));
        *(ushort4*)&Af[woff1] = oa;
        *(ushort4*)&Af[woff2] = ob;
        __syncthreads();
        if (s < 11 && srow_ok){
            pa = *(const float4*)(xrow + (s+1)*32);
            pb = *(const float4*)(xrow + (s+1)*32 + 4);
        }
        bf16x8 af[4];
        #pragma unroll
        for (int rt = 0; rt < 4; rt++)
            af[rt] = __builtin_bit_cast(bf16x8, *(const uint4*)&Af[(rt*64 + l)*8]);
        #pragma unroll
        for (int i = 0; i < 4; i++){
            bf16x8 bfr = __builtin_bit_cast(bf16x8,
                *(const uint4*)&Wf[((size_t)(s*16 + w*4 + i)*64 + l)*8]);
            #pragma unroll
            for (int rt = 0; rt < 4; rt++)
                acc[i][rt] = __builtin_amdgcn_mfma_f32_16x16x32_bf16(bfr, af[rt], acc[i][rt], 0, 0, 0);
        }
    }

    const int g = l >> 4;
    #pragma unroll
    for (int i = 0; i < 4; i++){
        int col = w*64 + i*16 + g*4;
        float4 cv = *(const float4*)&c1v[col];
        #pragma unroll
        for (int rt = 0; rt < 4; rt++){
            int node = n0 + rt*16 + (l & 15);
            if (node < N){
                f32x4 a = acc[i][rt];
                ushort4 o = make_ushort4(f2bf(a[0] + cv.x), f2bf(a[1] + cv.y),
                                         f2bf(a[2] + cv.z), f2bf(a[3] + cv.w));
                *(ushort4*)&h1[(size_t)node*C1 + col] = o;
            }
        }
    }
}

// ---------------- GEMM2 (MFMA): h2 = x2 @ W2, bf16 in/out ----------------
// block = 256 thr (4 waves), tile 128 rows x 128 cols; wave (wr,wc) -> 64x64
__global__ __launch_bounds__(256) void k_gemm2_mfma(const unsigned short* __restrict__ x2,
        const unsigned short* __restrict__ Wf, unsigned short* __restrict__ h2, int N)
{
    __shared__ unsigned short Af[8*64*8];
    const int tid = threadIdx.x;
    const int l   = tid & 63;
    const int w   = tid >> 6;
    const int wr  = w >> 1, wc = w & 1;
    const int n0  = blockIdx.x * 128;

    const int sr  = tid >> 2;
    const int sc  = (tid & 3) * 8;
    const int gb  = (tid & 1) * 2;
    const int jhi = (tid & 3) >> 1;
    const int base0 = (( (sr >> 4)*64       + (sr & 15) + 16*gb )*8) + jhi*4;
    const int base1 = (( ((sr+64) >> 4)*64  + (sr & 15) + 16*gb )*8) + jhi*4;
    const bool ok0 = (n0 + sr)      < N;
    const bool ok1 = (n0 + sr + 64) < N;

    f32x4 acc[4][4];
    #pragma unroll
    for (int i = 0; i < 4; i++)
        #pragma unroll
        for (int rt = 0; rt < 4; rt++)
            acc[i][rt] = (f32x4){0.f, 0.f, 0.f, 0.f};

    uint4 p0, p1;
    p0 = ok0 ? *(const uint4*)&x2[(size_t)(n0+sr   )*C1 + sc] : make_uint4(0,0,0,0);
    p1 = ok1 ? *(const uint4*)&x2[(size_t)(n0+sr+64)*C1 + sc] : make_uint4(0,0,0,0);

    for (int s = 0; s < 8; ++s){
        __syncthreads();
        *(uint2*)&Af[base0]       = make_uint2(p0.x, p0.y);
        *(uint2*)&Af[base0 + 128] = make_uint2(p0.z, p0.w);
        *(uint2*)&Af[base1]       = make_uint2(p1.x, p1.y);
        *(uint2*)&Af[base1 + 128] = make_uint2(p1.z, p1.w);
        __syncthreads();
        if (s < 7){
            p0 = ok0 ? *(const uint4*)&x2[(size_t)(n0+sr   )*C1 + (s+1)*32 + sc] : make_uint4(0,0,0,0);
            p1 = ok1 ? *(const uint4*)&x2[(size_t)(n0+sr+64)*C1 + (s+1)*32 + sc] : make_uint4(0,0,0,0);
        }
        bf16x8 af[4];
        #pragma unroll
        for (int rt = 0; rt < 4; rt++)
            af[rt] = __builtin_bit_cast(bf16x8, *(const uint4*)&Af[((wr*4 + rt)*64 + l)*8]);
        #pragma unroll
        for (int i = 0; i < 4; i++){
            bf16x8 bfr = __builtin_bit_cast(bf16x8,
                *(const uint4*)&Wf[((size_t)(s*8 + wc*4 + i)*64 + l)*8]);
            #pragma unroll
            for (int rt = 0; rt < 4; rt++)
                acc[i][rt] = __builtin_amdgcn_mfma_f32_16x16x32_bf16(bfr, af[rt], acc[i][rt], 0, 0, 0);
        }
    }

    const int g = l >> 4;
    #pragma unroll
    for (int i = 0; i < 4; i++){
        int col = wc*64 + i*16 + g*4;
        #pragma unroll
        for (int rt = 0; rt < 4; rt++){
            int node = n0 + wr*64 + rt*16 + (l & 15);
            if (node < N){
                f32x4 a = acc[i][rt];
                ushort4 o = make_ushort4(f2bf(a[0]), f2bf(a[1]), f2bf(a[2]), f2bf(a[3]));
                *(ushort4*)&h2[(size_t)node*C2 + col] = o;
            }
        }
    }
}

// ---------------- attention logits: al = einsum('nhc,hc->nh') ----------------
__global__ __launch_bounds__(256) void k_al1(const unsigned short* __restrict__ h1,
        const float* __restrict__ asrc, const float* __restrict__ adst,
        float* __restrict__ als, float* __restrict__ ald, int N)
{
    int lane = threadIdx.x & 63, wid = threadIdx.x >> 6;
    int n = blockIdx.x*4 + wid;
    if (n >= N) return;
    int c0 = lane*4, head = c0 >> 6, ca = c0 & 63;
    ushort4 v = *(const ushort4*)&h1[(size_t)n*C1 + c0];
    float h0 = bf2f(v.x), hb = bf2f(v.y), hc = bf2f(v.z), hd = bf2f(v.w);
    float4 a4 = *(const float4*)&asrc[head*HID + ca];
    float4 d4 = *(const float4*)&adst[head*HID + ca];
    float ps = h0*a4.x + hb*a4.y + hc*a4.z + hd*a4.w;
    float pd = h0*d4.x + hb*d4.y + hc*d4.z + hd*d4.w;
    #pragma unroll
    for (int m = 8; m >= 1; m >>= 1){
        ps += __shfl_xor(ps, m, 64);
        pd += __shfl_xor(pd, m, 64);
    }
    if ((lane & 15) == 0){ als[(size_t)n*4 + head] = ps; ald[(size_t)n*4 + head] = pd; }
}
__global__ __launch_bounds__(256) void k_al2(const unsigned short* __restrict__ h2,
        const float* __restrict__ asrc, const float* __restrict__ adst,
        float* __restrict__ als, float* __restrict__ ald, int N)
{
    int lane = threadIdx.x & 63, wid = threadIdx.x >> 6;
    int n = blockIdx.x*4 + wid;
    if (n >= N) return;
    int c0 = lane*2, head = c0 >> 6, ca = c0 & 63;
    uint32 v = *(const uint32*)&h2[(size_t)n*C2 + c0];
    float h0 = bf2f((unsigned short)(v & 0xffff)), hb = bf2f((unsigned short)(v >> 16));
    float2 a2 = *(const float2*)&asrc[head*HID + ca];
    float2 d2 = *(const float2*)&adst[head*HID + ca];
    float ps = h0*a2.x + hb*a2.y;
    float pd = h0*d2.x + hb*d2.y;
    #pragma unroll
    for (int m = 16; m >= 1; m >>= 1){
        ps += __shfl_xor(ps, m, 64);
        pd += __shfl_xor(pd, m, 64);
    }
    if ((lane & 31) == 0){ als[(size_t)n*2 + head] = ps; ald[(size_t)n*2 + head] = pd; }
}

// ---------------- per-node online-softmax aggregation (one wave per node) ----------
template<int HEADS, int CPL, int LAYER>
__global__ __launch_bounds__(256) void k_agg(const unsigned short* __restrict__ hlin,
        const float* __restrict__ als, const float* __restrict__ ald,
        const int* __restrict__ rowptr, const int* __restrict__ colx,
        const float* __restrict__ bias,
        const float* __restrict__ pad, const float* __restrict__ gw, const float* __restrict__ gb,
        unsigned short* __restrict__ out_bf, float* __restrict__ out_f, int N)
{
    constexpr int C = HEADS*64;
    int lane = threadIdx.x & 63, wid = threadIdx.x >> 6;
    int n = blockIdx.x*4 + wid;
    if (n >= N) return;
    int c0 = lane*CPL;
    int head = c0 >> 6;
    float myald = ald[(size_t)n*HEADS + head];
    float m = -INFINITY, den = 0.f;
    float acc[CPL];
    #pragma unroll
    for (int j = 0; j < CPL; j++) acc[j] = 0.f;
    int base = rowptr[n];
    int cnt = rowptr[n+1] - base;
    for (int i = -1; i < cnt; i++){          // i==-1 is the self loop
        int s = (i < 0) ? n : colx[base + i];
        float e = als[(size_t)s*HEADS + head] + myald;
        e = (e > 0.f) ? e : 0.2f*e;
        float mnew = fmaxf(m, e);
        float scale = __expf(m - mnew);
        float p = __expf(e - mnew);
        den = den*scale + p;
        float hv[CPL];
        if constexpr (CPL == 4){
            ushort4 v = *(const ushort4*)&hlin[(size_t)s*C + c0];
            hv[0] = bf2f(v.x); hv[1] = bf2f(v.y); hv[2] = bf2f(v.z); hv[3] = bf2f(v.w);
        } else {
            uint32 v = *(const uint32*)&hlin[(size_t)s*C + c0];
            hv[0] = bf2f((unsigned short)(v & 0xffff));
            hv[1] = bf2f((unsigned short)(v >> 16));
        }
        #pragma unroll
        for (int j = 0; j < CPL; j++) acc[j] = acc[j]*scale + p*hv[j];
        m = mnew;
    }
    float inv = 1.f/(den + 1e-16f);
    if constexpr (LAYER == 1){
        unsigned short o[CPL];
        #pragma unroll
        for (int j = 0; j < CPL; j++){
            float r = acc[j]*inv + bias[c0 + j];
            r = (r > 0.f) ? r : (__expf(r) - 1.f);   // elu
            o[j] = f2bf(r);
        }
        if constexpr (CPL == 4){
            ushort4 ov; ov.x = o[0]; ov.y = o[1]; ov.z = o[2]; ov.w = o[3];
            *(ushort4*)&out_bf[(size_t)n*C + c0] = ov;
        }
    } else {
        #pragma unroll
        for (int j = 0; j < CPL; j++){
            float r = acc[j]*inv + bias[c0 + j];
            r = (r > 0.f) ? r : (__expf(r) - 1.f);   // elu
            int cc = (c0 + j) & 63;
            float g = pad[0]*gw[0*HID + cc] + pad[1]*gw[1*HID + cc] + pad[2]*gw[2*HID + cc] + gb[cc];
            g = 1.f/(1.f + __expf(-g));              // constant emotion gate
            out_f[(size_t)n*C + c0 + j] = r*g;
        }
    }
}

// ---------------- attention-score MLP ----------------
__global__ __launch_bounds__(256) void k_attn(const float* __restrict__ hfin,
        const float* __restrict__ aw1, const float* __restrict__ ab1,
        const float* __restrict__ aw2, const float* __restrict__ ab2,
        float* __restrict__ attn, int N)
{
    __shared__ float hs[4][C2];
    int lane = threadIdx.x & 63, wid = threadIdx.x >> 6;
    int n = blockIdx.x*4 + wid;
    bool valid = (n < N);
    if (valid){
        float2 v = *(const float2*)&hfin[(size_t)n*C2 + lane*2];
        hs[wid][lane*2]   = v.x;
        hs[wid][lane*2+1] = v.y;
    }
    __syncthreads();
    if (!valid) return;
    float a = ab1[lane];
    #pragma unroll 4
    for (int c = 0; c < C2; c++) a += hs[wid][c]*aw1[(size_t)c*HID + lane];
    a = fmaxf(a, 0.f);
    float part = a*aw2[lane];
    #pragma unroll
    for (int m = 32; m >= 1; m >>= 1) part += __shfl_xor(part, m, 64);
    if (lane == 0) attn[n] = 1.f/(1.f + __expf(-(part + ab2[0])));
}

extern "C" void kernel_launch(void* const* d_in, const int* in_sizes, int n_in,
                              void* d_out, int out_size, void* d_ws, size_t ws_size,
                              hipStream_t stream)
{
    const float* x    = (const float*)d_in[0];
    const int*   ei   = (const int*)  d_in[1];
    const float* pad  = (const float*)d_in[2];
    const float* W1   = (const float*)d_in[3];
    const float* as1  = (const float*)d_in[4];
    const float* ad1  = (const float*)d_in[5];
    const float* b1   = (const float*)d_in[6];
    const float* W2   = (const float*)d_in[7];
    const float* as2  = (const float*)d_in[8];
    const float* ad2  = (const float*)d_in[9];
    const float* b2   = (const float*)d_in[10];
    const float* aw1  = (const float*)d_in[11];
    const float* ab1  = (const float*)d_in[12];
    const float* aw2  = (const float*)d_in[13];
    const float* ab2  = (const float*)d_in[14];
    const float* gw   = (const float*)d_in[15];
    const float* gb   = (const float*)d_in[16];

    const int N = in_sizes[0] / IN_DIM;
    const int E = in_sizes[1] / 2;

    float* outh    = (float*)d_out;
    float* outattn = outh + (size_t)N*C2;

    char* w = (char*)d_ws;
    auto alloc = [&](size_t bytes)->char*{
        char* p = w;
        w += (bytes + 255) & ~(size_t)255;
        return p;
    };
    unsigned short* h1  = (unsigned short*)alloc((size_t)N*C1*2);
    unsigned short* x2  = (unsigned short*)alloc((size_t)N*C1*2);
    unsigned short* h2  = (unsigned short*)alloc((size_t)N*C2*2);
    float* als1 = (float*)alloc((size_t)N*4*4);
    float* ald1 = (float*)alloc((size_t)N*4*4);
    float* als2 = (float*)alloc((size_t)N*2*4);
    float* ald2 = (float*)alloc((size_t)N*2*4);
    int* deg    = (int*)alloc((size_t)N*4);
    int* cur    = (int*)alloc((size_t)N*4);
    int* rowptr = (int*)alloc((size_t)(N+1)*4);
    int* colx   = (int*)alloc((size_t)E*4);
    int* part   = (int*)alloc(512*4);
    unsigned short* Wf1 = (unsigned short*)alloc((size_t)12*16*64*8*2);
    unsigned short* Wf2 = (unsigned short*)alloc((size_t)8*8*64*8*2);
    float* c1v  = (float*)alloc(C1*4);

    const int nbN = (N + 255)/256;
    const int nbE = (E + 255)/256;
    const int nbW = (N + 3)/4;       // wave-per-node kernels
    const int nbG1 = (N + 63)/64;    // gemm1 row blocks
    const int nbG2 = (N + 127)/128;  // gemm2 row blocks

    // weight swizzles + pad bias (independent of CSR)
    k_cvtW   <<<(192+3)/4, 256, 0, stream>>>(W1, Wf1, C1, 16, 192);
    k_cvtW   <<<(64+3)/4,  256, 0, stream>>>(W2, Wf2, C2, 8, 64);
    k_padbias<<<1, 256, 0, stream>>>(W1, pad, c1v);

    // CSR by destination
    k_zero   <<<nbN, 256, 0, stream>>>(deg, cur, N);
    k_hist   <<<nbE, 256, 0, stream>>>(ei, deg, E);
    k_scan1  <<<nbN, 256, 0, stream>>>(deg, rowptr, part, N);
    k_scan2  <<<1, 512, 0, stream>>>(part, nbN);
    k_scan3  <<<nbN, 256, 0, stream>>>(rowptr, part, N, E);
    k_scatter<<<nbE, 256, 0, stream>>>(ei, rowptr, cur, colx, E);

    k_gemm1_mfma<<<nbG1, 256, 0, stream>>>(x, Wf1, c1v, h1, N);
    k_al1  <<<nbW, 256, 0, stream>>>(h1, as1, ad1, als1, ald1, N);
    k_agg<4,4,1><<<nbW, 256, 0, stream>>>(h1, als1, ald1, rowptr, colx, b1,
                                          nullptr, nullptr, nullptr, x2, nullptr, N);

    k_gemm2_mfma<<<nbG2, 256, 0, stream>>>(x2, Wf2, h2, N);
    k_al2  <<<nbW, 256, 0, stream>>>(h2, as2, ad2, als2, ald2, N);
    k_agg<2,2,2><<<nbW, 256, 0, stream>>>(h2, als2, ald2, rowptr, colx, b2,
                                          pad, gw, gb, nullptr, outh, N);

    k_attn <<<nbW, 256, 0, stream>>>(outh, aw1, ab1, aw2, ab2, outattn, N);
}

// Round 3
// 431.833 us; speedup vs baseline: 1.7131x; 1.0384x over previous
//
#include <hip/hip_runtime.h>
#include <hip/hip_bf16.h>
#include <stdint.h>

#define IN_DIM 384
#define HID 64
#define C1 256   // 4 heads * 64
#define C2 128   // 2 heads * 64

typedef unsigned int uint32;
typedef __bf16 bf16x8 __attribute__((ext_vector_type(8)));
typedef float f32x4 __attribute__((ext_vector_type(4)));

static __device__ __forceinline__ float bf2f(unsigned short u){
    return __uint_as_float(((uint32)u) << 16);
}
static __device__ __forceinline__ unsigned short f2bf(float x){
    uint32 u = __float_as_uint(x);
    return (unsigned short)((u + 0x7FFFu + ((u >> 16) & 1u)) >> 16);
}
static __device__ __forceinline__ uint32 pack2(float a, float b){
    return (uint32)f2bf(a) | ((uint32)f2bf(b) << 16);
}

// ---------------- CSR build ----------------
__global__ void k_zero(int* deg, int* cur, int N){
    int i = blockIdx.x*256 + threadIdx.x;
    if (i < N){ deg[i] = 0; cur[i] = 0; }
}
__global__ void k_hist(const int* __restrict__ ei, int* deg, int E){
    int i = blockIdx.x*256 + threadIdx.x;
    if (i < E) atomicAdd(&deg[ei[E + i]], 1);
}
__global__ void k_scan1(const int* __restrict__ deg, int* rowptr, int* part, int N){
    __shared__ int s[256];
    int tid = threadIdx.x;
    int i = blockIdx.x*256 + tid;
    int v = (i < N) ? deg[i] : 0;
    s[tid] = v; __syncthreads();
    for (int off = 1; off < 256; off <<= 1){
        int t = (tid >= off) ? s[tid - off] : 0;
        __syncthreads();
        s[tid] += t;
        __syncthreads();
    }
    if (i < N) rowptr[i] = s[tid] - v;
    if (tid == 255) part[blockIdx.x] = s[tid];
}
__global__ void k_scan2(int* part, int nb){
    __shared__ int s[512];
    int tid = threadIdx.x;
    int v = (tid < nb) ? part[tid] : 0;
    s[tid] = v; __syncthreads();
    for (int off = 1; off < 512; off <<= 1){
        int t = (tid >= off) ? s[tid - off] : 0;
        __syncthreads();
        s[tid] += t;
        __syncthreads();
    }
    if (tid < nb) part[tid] = s[tid] - v;
}
__global__ void k_scan3(int* rowptr, const int* __restrict__ part, int N, int E){
    int i = blockIdx.x*256 + threadIdx.x;
    if (i < N) rowptr[i] += part[blockIdx.x];
    if (i == 0) rowptr[N] = E;
}
__global__ void k_scatter(const int* __restrict__ ei, const int* __restrict__ rowptr,
                          int* cur, int* colx, int E){
    int i = blockIdx.x*256 + threadIdx.x;
    if (i < E){
        int d = ei[E + i];
        int pos = atomicAdd(&cur[d], 1);
        colx[rowptr[d] + pos] = ei[i];
    }
}

// ---------------- weight pre-swizzle: contiguous-k fragment order ----------------
// Wf[unit = s*ntiles+ct][lane l][j] = W[k = s*32 + 8*(l>>4) + j][ct*16 + (l&15)]
__global__ __launch_bounds__(256) void k_cvtW(const float* __restrict__ W,
        unsigned short* __restrict__ Wf, int ncol, int ntiles, int nunits){
    int unit = blockIdx.x*4 + (threadIdx.x >> 6);
    if (unit >= nunits) return;
    int l = threadIdx.x & 63;
    int s = unit / ntiles, ct = unit % ntiles;
    int col = ct*16 + (l & 15);
    int g = l >> 4;
    unsigned short o[8];
    #pragma unroll
    for (int j = 0; j < 8; j++){
        int k = s*32 + g*8 + j;
        o[j] = f2bf(W[(size_t)k*ncol + col]);
    }
    ushort4* dst = (ushort4*)&Wf[((size_t)unit*64 + l)*8];
    dst[0] = make_ushort4(o[0], o[1], o[2], o[3]);
    dst[1] = make_ushort4(o[4], o[5], o[6], o[7]);
}

__global__ void k_padbias(const float* __restrict__ W1, const float* __restrict__ pad,
                          float* __restrict__ c1v){
    int c = threadIdx.x;
    c1v[c] = pad[0]*W1[(size_t)(IN_DIM+0)*C1 + c]
           + pad[1]*W1[(size_t)(IN_DIM+1)*C1 + c]
           + pad[2]*W1[(size_t)(IN_DIM+2)*C1 + c];
}

// ---------------- GEMM1 (MFMA): h1 = [x|pad]@W1 + fused al1 epilogue ----------------
// 128 rows x 256 cols per block, 4 waves, wave w -> head w (cols w*64..+64), dbuf LDS, 1 barrier/step
__global__ __launch_bounds__(256) void k_gemm1_mfma(const float* __restrict__ x,
        const unsigned short* __restrict__ Wf, const float* __restrict__ c1v,
        const float* __restrict__ as1, const float* __restrict__ ad1,
        unsigned short* __restrict__ h1, float* __restrict__ als, float* __restrict__ ald, int N)
{
    __shared__ unsigned short Af[2][8*64*8];   // 2 x 8KB
    const int tid = threadIdx.x;
    const int l   = tid & 63;
    const int w   = tid >> 6;
    const int n0  = blockIdx.x * 128;

    // staging: thread covers row (tid&127), k-half (tid>>7)*16 of the 32-wide step (64B load)
    const int srow = tid & 127;
    const int jh   = tid >> 7;
    const int srt  = srow >> 4, srr = srow & 15;
    const int d0   = (srt*64 + (jh*2+0)*16 + srr)*8;
    const int d1   = (srt*64 + (jh*2+1)*16 + srr)*8;
    int crow = n0 + srow; if (crow > N-1) crow = N-1;
    const float* xrow = x + (size_t)crow*IN_DIM + jh*16;

    f32x4 acc[4][8];
    #pragma unroll
    for (int i = 0; i < 4; i++)
        #pragma unroll
        for (int rt = 0; rt < 8; rt++)
            acc[i][rt] = (f32x4){0.f, 0.f, 0.f, 0.f};

    float4 ra, rb, rc, rd;
    uint4 wcur[4], wnxt[4];

    // prologue: stage s=0, preload W s=0
    ra = *(const float4*)(xrow + 0); rb = *(const float4*)(xrow + 4);
    rc = *(const float4*)(xrow + 8); rd = *(const float4*)(xrow + 12);
    {
        uint4 u0, u1;
        u0.x = pack2(ra.x, ra.y); u0.y = pack2(ra.z, ra.w);
        u0.z = pack2(rb.x, rb.y); u0.w = pack2(rb.z, rb.w);
        u1.x = pack2(rc.x, rc.y); u1.y = pack2(rc.z, rc.w);
        u1.z = pack2(rd.x, rd.y); u1.w = pack2(rd.z, rd.w);
        *(uint4*)&Af[0][d0] = u0;
        *(uint4*)&Af[0][d1] = u1;
    }
    {
        const unsigned short* p = Wf + ((size_t)(w*4)*64 + l)*8;
        #pragma unroll
        for (int i = 0; i < 4; i++) wcur[i] = *(const uint4*)(p + (size_t)i*512);
    }
    __syncthreads();

    for (int s = 0; s < 12; ++s){
        if (s < 11){
            const float* src = xrow + (s+1)*32;
            ra = *(const float4*)(src + 0); rb = *(const float4*)(src + 4);
            rc = *(const float4*)(src + 8); rd = *(const float4*)(src + 12);
            const unsigned short* p = Wf + ((size_t)((s+1)*16 + w*4)*64 + l)*8;
            #pragma unroll
            for (int i = 0; i < 4; i++) wnxt[i] = *(const uint4*)(p + (size_t)i*512);
        }
        bf16x8 af[8];
        #pragma unroll
        for (int rt = 0; rt < 8; rt++)
            af[rt] = __builtin_bit_cast(bf16x8, *(const uint4*)&Af[s&1][(rt*64 + l)*8]);
        #pragma unroll
        for (int i = 0; i < 4; i++){
            bf16x8 bw = __builtin_bit_cast(bf16x8, wcur[i]);
            #pragma unroll
            for (int rt = 0; rt < 8; rt++)
                acc[i][rt] = __builtin_amdgcn_mfma_f32_16x16x32_bf16(bw, af[rt], acc[i][rt], 0, 0, 0);
        }
        if (s < 11){
            uint4 u0, u1;
            u0.x = pack2(ra.x, ra.y); u0.y = pack2(ra.z, ra.w);
            u0.z = pack2(rb.x, rb.y); u0.w = pack2(rb.z, rb.w);
            u1.x = pack2(rc.x, rc.y); u1.y = pack2(rc.z, rc.w);
            u1.z = pack2(rd.x, rd.y); u1.w = pack2(rd.z, rd.w);
            *(uint4*)&Af[(s+1)&1][d0] = u0;
            *(uint4*)&Af[(s+1)&1][d1] = u1;
            __syncthreads();
            #pragma unroll
            for (int i = 0; i < 4; i++) wcur[i] = wnxt[i];
        }
    }

    // fused epilogue: h1 store + al1 (head w)
    const int g = l >> 4;
    float4 cvv[4], av[4], dv[4];
    #pragma unroll
    for (int i = 0; i < 4; i++){
        int cl = i*16 + g*4;
        cvv[i] = *(const float4*)&c1v[w*64 + cl];
        av[i]  = *(const float4*)&as1[w*64 + cl];
        dv[i]  = *(const float4*)&ad1[w*64 + cl];
    }
    #pragma unroll
    for (int rt = 0; rt < 8; rt++){
        int node = n0 + rt*16 + (l & 15);
        bool ok = node < N;
        float ps = 0.f, pd = 0.f;
        #pragma unroll
        for (int i = 0; i < 4; i++){
            float h0 = acc[i][rt][0] + cvv[i].x;
            float h1v = acc[i][rt][1] + cvv[i].y;
            float h2v = acc[i][rt][2] + cvv[i].z;
            float h3v = acc[i][rt][3] + cvv[i].w;
            ps += h0*av[i].x + h1v*av[i].y + h2v*av[i].z + h3v*av[i].w;
            pd += h0*dv[i].x + h1v*dv[i].y + h2v*dv[i].z + h3v*dv[i].w;
            if (ok){
                ushort4 o = make_ushort4(f2bf(h0), f2bf(h1v), f2bf(h2v), f2bf(h3v));
                *(ushort4*)&h1[(size_t)node*C1 + w*64 + i*16 + g*4] = o;
            }
        }
        ps += __shfl_xor(ps, 16, 64); ps += __shfl_xor(ps, 32, 64);
        pd += __shfl_xor(pd, 16, 64); pd += __shfl_xor(pd, 32, 64);
        if (ok && g == 0){
            als[(size_t)node*4 + w] = ps;
            ald[(size_t)node*4 + w] = pd;
        }
    }
}

// ---------------- GEMM2 (MFMA): h2 = x2 @ W2 + fused al2 epilogue ----------------
// 128 rows x 128 cols, 4 waves: wc = w&1 (head), wr = w>>1 (row half)
__global__ __launch_bounds__(256) void k_gemm2_mfma(const unsigned short* __restrict__ x2,
        const unsigned short* __restrict__ Wf,
        const float* __restrict__ as2, const float* __restrict__ ad2,
        unsigned short* __restrict__ h2, float* __restrict__ als, float* __restrict__ ald, int N)
{
    __shared__ unsigned short Af[2][8*64*8];
    const int tid = threadIdx.x;
    const int l   = tid & 63;
    const int w   = tid >> 6;
    const int wr  = w >> 1, wc = w & 1;
    const int n0  = blockIdx.x * 128;

    // staging: thread covers row tid>>1, k-half (tid&1)*16 (32B load)
    const int srow = tid >> 1;
    const int half = tid & 1;
    const int srt  = srow >> 4, srr = srow & 15;
    const int d0   = (srt*64 + (half*2+0)*16 + srr)*8;
    const int d1   = d0 + 128;
    int crow = n0 + srow; if (crow > N-1) crow = N-1;
    const unsigned short* xrow = x2 + (size_t)crow*C1 + half*16;

    f32x4 acc[4][4];
    #pragma unroll
    for (int i = 0; i < 4; i++)
        #pragma unroll
        for (int rt = 0; rt < 4; rt++)
            acc[i][rt] = (f32x4){0.f, 0.f, 0.f, 0.f};

    uint4 p0, p1, wcur[4], wnxt[4];
    p0 = *(const uint4*)(xrow + 0);
    p1 = *(const uint4*)(xrow + 8);
    *(uint4*)&Af[0][d0] = p0;
    *(uint4*)&Af[0][d1] = p1;
    {
        const unsigned short* p = Wf + ((size_t)(wc*4)*64 + l)*8;
        #pragma unroll
        for (int i = 0; i < 4; i++) wcur[i] = *(const uint4*)(p + (size_t)i*512);
    }
    __syncthreads();

    for (int s = 0; s < 8; ++s){
        if (s < 7){
            p0 = *(const uint4*)(xrow + (s+1)*32);
            p1 = *(const uint4*)(xrow + (s+1)*32 + 8);
            const unsigned short* p = Wf + ((size_t)((s+1)*8 + wc*4)*64 + l)*8;
            #pragma unroll
            for (int i = 0; i < 4; i++) wnxt[i] = *(const uint4*)(p + (size_t)i*512);
        }
        bf16x8 af[4];
        #pragma unroll
        for (int rt = 0; rt < 4; rt++)
            af[rt] = __builtin_bit_cast(bf16x8, *(const uint4*)&Af[s&1][((wr*4 + rt)*64 + l)*8]);
        #pragma unroll
        for (int i = 0; i < 4; i++){
            bf16x8 bw = __builtin_bit_cast(bf16x8, wcur[i]);
            #pragma unroll
            for (int rt = 0; rt < 4; rt++)
                acc[i][rt] = __builtin_amdgcn_mfma_f32_16x16x32_bf16(bw, af[rt], acc[i][rt], 0, 0, 0);
        }
        if (s < 7){
            *(uint4*)&Af[(s+1)&1][d0] = p0;
            *(uint4*)&Af[(s+1)&1][d1] = p1;
            __syncthreads();
            #pragma unroll
            for (int i = 0; i < 4; i++) wcur[i] = wnxt[i];
        }
    }

    const int g = l >> 4;
    float4 av[4], dv[4];
    #pragma unroll
    for (int i = 0; i < 4; i++){
        int cl = i*16 + g*4;
        av[i] = *(const float4*)&as2[wc*64 + cl];
        dv[i] = *(const float4*)&ad2[wc*64 + cl];
    }
    #pragma unroll
    for (int rt = 0; rt < 4; rt++){
        int node = n0 + wr*64 + rt*16 + (l & 15);
        bool ok = node < N;
        float ps = 0.f, pd = 0.f;
        #pragma unroll
        for (int i = 0; i < 4; i++){
            float h0 = acc[i][rt][0], h1v = acc[i][rt][1];
            float h2v = acc[i][rt][2], h3v = acc[i][rt][3];
            ps += h0*av[i].x + h1v*av[i].y + h2v*av[i].z + h3v*av[i].w;
            pd += h0*dv[i].x + h1v*dv[i].y + h2v*dv[i].z + h3v*dv[i].w;
            if (ok){
                ushort4 o = make_ushort4(f2bf(h0), f2bf(h1v), f2bf(h2v), f2bf(h3v));
                *(ushort4*)&h2[(size_t)node*C2 + wc*64 + i*16 + g*4] = o;
            }
        }
        ps += __shfl_xor(ps, 16, 64); ps += __shfl_xor(ps, 32, 64);
        pd += __shfl_xor(pd, 16, 64); pd += __shfl_xor(pd, 32, 64);
        if (ok && g == 0){
            als[(size_t)node*2 + wc] = ps;
            ald[(size_t)node*2 + wc] = pd;
        }
    }
}

// ---------------- per-node online-softmax aggregation (one wave per node) ----------
// 1-deep software pipeline on the edge gather; LAYER==2 fuses gate + attn-MLP
template<int HEADS, int CPL, int LAYER>
__global__ __launch_bounds__(256) void k_agg(const unsigned short* __restrict__ hlin,
        const float* __restrict__ als, const float* __restrict__ ald,
        const int* __restrict__ rowptr, const int* __restrict__ colx,
        const float* __restrict__ bias,
        const float* __restrict__ pad, const float* __restrict__ gw, const float* __restrict__ gb,
        const float* __restrict__ aw1, const float* __restrict__ ab1,
        const float* __restrict__ aw2, const float* __restrict__ ab2,
        unsigned short* __restrict__ out_bf, float* __restrict__ out_f,
        float* __restrict__ attn, int N)
{
    constexpr int C = HEADS*64;
    __shared__ float hs[4][C2];
    int lane = threadIdx.x & 63, wid = threadIdx.x >> 6;
    int n = blockIdx.x*4 + wid;
    bool valid = (n < N);
    if (valid){
        int c0 = lane*CPL;
        int head = c0 >> 6;
        float myald = ald[(size_t)n*HEADS + head];
        float m = -INFINITY, den = 0.f;
        float acc[CPL];
        #pragma unroll
        for (int j = 0; j < CPL; j++) acc[j] = 0.f;
        int base = rowptr[n];
        int cnt = rowptr[n+1] - base;

        // current = self loop
        float eRaw = als[(size_t)n*HEADS + head];
        float hv[CPL];
        if constexpr (CPL == 4){
            ushort4 v = *(const ushort4*)&hlin[(size_t)n*C + c0];
            hv[0] = bf2f(v.x); hv[1] = bf2f(v.y); hv[2] = bf2f(v.z); hv[3] = bf2f(v.w);
        } else {
            uint32 v = *(const uint32*)&hlin[(size_t)n*C + c0];
            hv[0] = bf2f((unsigned short)(v & 0xffff));
            hv[1] = bf2f((unsigned short)(v >> 16));
        }
        for (int i = 0; i <= cnt; i++){
            // prefetch next edge while current is processed
            float eNraw = 0.f;
            float hvN[CPL];
            #pragma unroll
            for (int j = 0; j < CPL; j++) hvN[j] = 0.f;
            if (i < cnt){
                int sN = colx[base + i];
                eNraw = als[(size_t)sN*HEADS + head];
                if constexpr (CPL == 4){
                    ushort4 v = *(const ushort4*)&hlin[(size_t)sN*C + c0];
                    hvN[0] = bf2f(v.x); hvN[1] = bf2f(v.y); hvN[2] = bf2f(v.z); hvN[3] = bf2f(v.w);
                } else {
                    uint32 v = *(const uint32*)&hlin[(size_t)sN*C + c0];
                    hvN[0] = bf2f((unsigned short)(v & 0xffff));
                    hvN[1] = bf2f((unsigned short)(v >> 16));
                }
            }
            float e = eRaw + myald;
            e = (e > 0.f) ? e : 0.2f*e;
            float mnew = fmaxf(m, e);
            float scale = __expf(m - mnew);
            float p = __expf(e - mnew);
            den = den*scale + p;
            #pragma unroll
            for (int j = 0; j < CPL; j++) acc[j] = acc[j]*scale + p*hv[j];
            m = mnew;
            eRaw = eNraw;
            #pragma unroll
            for (int j = 0; j < CPL; j++) hv[j] = hvN[j];
        }
        float inv = 1.f/(den + 1e-16f);
        if constexpr (LAYER == 1){
            unsigned short o[CPL];
            #pragma unroll
            for (int j = 0; j < CPL; j++){
                float r = acc[j]*inv + bias[c0 + j];
                r = (r > 0.f) ? r : (__expf(r) - 1.f);   // elu
                o[j] = f2bf(r);
            }
            if constexpr (CPL == 4){
                ushort4 ov; ov.x = o[0]; ov.y = o[1]; ov.z = o[2]; ov.w = o[3];
                *(ushort4*)&out_bf[(size_t)n*C + c0] = ov;
            }
        } else {
            #pragma unroll
            for (int j = 0; j < CPL; j++){
                float r = acc[j]*inv + bias[c0 + j];
                r = (r > 0.f) ? r : (__expf(r) - 1.f);   // elu
                int cc = (c0 + j) & 63;
                float gt = pad[0]*gw[0*HID + cc] + pad[1]*gw[1*HID + cc] + pad[2]*gw[2*HID + cc] + gb[cc];
                gt = 1.f/(1.f + __expf(-gt));            // constant emotion gate
                float o = r*gt;
                out_f[(size_t)n*C + c0 + j] = o;
                hs[wid][c0 + j] = o;
            }
            // fused attention-score MLP (wave-local LDS row; no cross-wave sharing)
            float a = ab1[lane];
            #pragma unroll 4
            for (int c = 0; c < C2; c++) a += hs[wid][c]*aw1[(size_t)c*HID + lane];
            a = fmaxf(a, 0.f);
            float part = a*aw2[lane];
            #pragma unroll
            for (int mm = 32; mm >= 1; mm >>= 1) part += __shfl_xor(part, mm, 64);
            if (lane == 0) attn[n] = 1.f/(1.f + __expf(-(part + ab2[0])));
        }
    }
}

extern "C" void kernel_launch(void* const* d_in, const int* in_sizes, int n_in,
                              void* d_out, int out_size, void* d_ws, size_t ws_size,
                              hipStream_t stream)
{
    const float* x    = (const float*)d_in[0];
    const int*   ei   = (const int*)  d_in[1];
    const float* pad  = (const float*)d_in[2];
    const float* W1   = (const float*)d_in[3];
    const float* as1  = (const float*)d_in[4];
    const float* ad1  = (const float*)d_in[5];
    const float* b1   = (const float*)d_in[6];
    const float* W2   = (const float*)d_in[7];
    const float* as2  = (const float*)d_in[8];
    const float* ad2  = (const float*)d_in[9];
    const float* b2   = (const float*)d_in[10];
    const float* aw1  = (const float*)d_in[11];
    const float* ab1  = (const float*)d_in[12];
    const float* aw2  = (const float*)d_in[13];
    const float* ab2  = (const float*)d_in[14];
    const float* gw   = (const float*)d_in[15];
    const float* gb   = (const float*)d_in[16];

    const int N = in_sizes[0] / IN_DIM;
    const int E = in_sizes[1] / 2;

    float* outh    = (float*)d_out;
    float* outattn = outh + (size_t)N*C2;

    char* w = (char*)d_ws;
    auto alloc = [&](size_t bytes)->char*{
        char* p = w;
        w += (bytes + 255) & ~(size_t)255;
        return p;
    };
    unsigned short* h1  = (unsigned short*)alloc((size_t)N*C1*2);
    unsigned short* x2  = (unsigned short*)alloc((size_t)N*C1*2);
    unsigned short* h2  = (unsigned short*)alloc((size_t)N*C2*2);
    float* als1 = (float*)alloc((size_t)N*4*4);
    float* ald1 = (float*)alloc((size_t)N*4*4);
    float* als2 = (float*)alloc((size_t)N*2*4);
    float* ald2 = (float*)alloc((size_t)N*2*4);
    int* deg    = (int*)alloc((size_t)N*4);
    int* cur    = (int*)alloc((size_t)N*4);
    int* rowptr = (int*)alloc((size_t)(N+1)*4);
    int* colx   = (int*)alloc((size_t)E*4);
    int* part   = (int*)alloc(512*4);
    unsigned short* Wf1 = (unsigned short*)alloc((size_t)12*16*64*8*2);
    unsigned short* Wf2 = (unsigned short*)alloc((size_t)8*8*64*8*2);
    float* c1v  = (float*)alloc(C1*4);

    const int nbN = (N + 255)/256;
    const int nbE = (E + 255)/256;
    const int nbW = (N + 3)/4;        // wave-per-node kernels
    const int nbG = (N + 127)/128;    // gemm row blocks

    // weight swizzles + pad bias (independent of CSR)
    k_cvtW   <<<(192+3)/4, 256, 0, stream>>>(W1, Wf1, C1, 16, 192);
    k_cvtW   <<<(64+3)/4,  256, 0, stream>>>(W2, Wf2, C2, 8, 64);
    k_padbias<<<1, 256, 0, stream>>>(W1, pad, c1v);

    // CSR by destination
    k_zero   <<<nbN, 256, 0, stream>>>(deg, cur, N);
    k_hist   <<<nbE, 256, 0, stream>>>(ei, deg, E);
    k_scan1  <<<nbN, 256, 0, stream>>>(deg, rowptr, part, N);
    k_scan2  <<<1, 512, 0, stream>>>(part, nbN);
    k_scan3  <<<nbN, 256, 0, stream>>>(rowptr, part, N, E);
    k_scatter<<<nbE, 256, 0, stream>>>(ei, rowptr, cur, colx, E);

    k_gemm1_mfma<<<nbG, 256, 0, stream>>>(x, Wf1, c1v, as1, ad1, h1, als1, ald1, N);
    k_agg<4,4,1><<<nbW, 256, 0, stream>>>(h1, als1, ald1, rowptr, colx, b1,
                                          nullptr, nullptr, nullptr,
                                          nullptr, nullptr, nullptr, nullptr,
                                          x2, nullptr, nullptr, N);

    k_gemm2_mfma<<<nbG, 256, 0, stream>>>(x2, Wf2, as2, ad2, h2, als2, ald2, N);
    k_agg<2,2,2><<<nbW, 256, 0, stream>>>(h2, als2, ald2, rowptr, colx, b2,
                                          pad, gw, gb,
                                          aw1, ab1, aw2, ab2,
                                          nullptr, outh, outattn, N);
}